// Round 11
// baseline (650.386 us; speedup 1.0000x reference)
//
#include <hip/hip_runtime.h>
#include <hip/hip_fp16.h>
#include <hip/hip_cooperative_groups.h>
#include <stdint.h>

namespace cg = cooperative_groups;

// GCN: out = relu(Ahat @ (X W1) + b1) -> relu(Ahat @ (. W2) + b2) -> @ Wfc + bfc
// Ahat = D^-1/2 (A+I) D^-1/2.
// Identity: layer(v) = dis[v] * ( sum_{e: dst=v} hs[src_e] + hs[v] ),
// hs[i] = (x[i] @ W) * dis[i].  Self-loops analytic.
//
// Cost model (R1..R10 measured):
//  - atomic-free CSR aggregation (R6), fp16 hs tables < 4MB XCD L2 (R8);
//  - ~half of remaining wall time is the 6-launch serial dispatch chain (R9);
//  - R10: hand-sized cooperative grid (768) was rejected silently -> R11
//    queries occupancy at runtime, checks the launch rc, and falls back to
//    the proven 6-kernel chain when cooperative launch is unavailable.

constexpr int F = 16;
constexpr int K_MAX = 256;           // max buckets
constexpr int BNODES = 512;          // nodes per bucket  (bucket = dst >> 9)
constexpr int PT = 2048;             // edges per partition tile (8/thread)
constexpr int NPB = 128;             // nodes per chunk in aggregation
constexpr unsigned int CAP = 18432;  // bucket capacity (mean 16327, +16 sigma)

struct SU {
    union {
        struct {
            unsigned int hist[K_MAX], offs[K_MAX], gbase[K_MAX];
            unsigned int drec[PT];
            unsigned char dbuk[PT];
        } part;                                   // 13.0 KB
        struct { unsigned int cur[BNODES]; unsigned int wsum[4]; } sort;
        struct { float ws[16][16]; float xs[16][17]; } mv;
        struct { float ws[16][16]; float hbf[NPB][17]; } agg;
    };
};

__device__ __forceinline__ float2 h2f2(__half2 h) { return __half22float2(h); }

// ======================= fused cooperative kernel ========================
__global__ void __launch_bounds__(256, 4)
fused_kernel(const int* __restrict__ src, const int* __restrict__ dst,
             const float* __restrict__ x,
             const float* __restrict__ W1, const float* __restrict__ b1,
             const float* __restrict__ W2, const float* __restrict__ b2,
             const float* __restrict__ Wfc, const float* __restrict__ bfc,
             float* __restrict__ out,
             unsigned int* __restrict__ gcur, unsigned int* __restrict__ rp,
             unsigned int* __restrict__ recs, unsigned int* __restrict__ recs2,
             float* __restrict__ dis, __half* __restrict__ hs1, __half* __restrict__ hs2,
             int N, int E, int K) {
    __shared__ SU su;
    cg::grid_group grid = cg::this_grid();
    const int t = threadIdx.x;
    const int blk = blockIdx.x;
    const int nblk = gridDim.x;

    // ---- phase 0: init bucket cursors -----------------------------------
    {
        int gid = blk * 256 + t;
        if (gid < K) gcur[gid] = (unsigned int)gid * CAP;
    }
    grid.sync();

    // ---- phase 1: deterministic tile partition (bucket-grouped recs) ----
    {
        const int ntiles = (E + PT - 1) / PT;
        for (int tile = blk; tile < ntiles; tile += nblk) {
            const int tile0 = tile * PT;
            const int cnt = min(PT, E - tile0);
            if (t < K) su.part.hist[t] = 0u;
            __syncthreads();
            unsigned int rec[8], bp[8];
#pragma unroll
            for (int k = 0; k < 8; ++k) {
                int i = t + k * 256;              // coalesced
                bp[k] = 0xFFFFFFFFu;
                if (i < cnt) {
                    int e = tile0 + i;
                    unsigned int d = (unsigned int)dst[e];
                    unsigned int s = (unsigned int)src[e];
                    unsigned int b = d >> 9;
                    rec[k] = ((d & 511u) << 17) | s;
                    unsigned int pos = atomicAdd(&su.part.hist[b], 1u);  // <2048
                    bp[k] = (b << 12) | pos;
                }
            }
            __syncthreads();
            if (t < K) su.part.gbase[t] = atomicAdd(&gcur[t], su.part.hist[t]);
            if (t == 0) {
                unsigned int run = 0;
                for (int i = 0; i < K; ++i) { su.part.offs[i] = run; run += su.part.hist[i]; }
            }
            __syncthreads();
#pragma unroll
            for (int k = 0; k < 8; ++k) {
                if (bp[k] != 0xFFFFFFFFu) {
                    unsigned int b = bp[k] >> 12, pos = bp[k] & 0xFFFu;
                    unsigned int idx = su.part.offs[b] + pos;
                    su.part.drec[idx] = rec[k];
                    su.part.dbuk[idx] = (unsigned char)b;
                }
            }
            __syncthreads();
            for (int i = t; i < cnt; i += 256) {  // coalesced within runs
                unsigned int b = su.part.dbuk[i];
                recs[su.part.gbase[b] + ((unsigned int)i - su.part.offs[b])] = su.part.drec[i];
            }
            __syncthreads();                      // protect LDS for next tile
        }
    }
    grid.sync();

    // ---- phase 2: in-bucket counting sort -> CSR + dis + packed rows ----
    {
        const int lane = t & 63, wid = t >> 6;
        for (int b = blk; b < K; b += nblk) {
            su.sort.cur[2 * t] = 0u;
            su.sort.cur[2 * t + 1] = 0u;
            __syncthreads();
            const unsigned int e0 = (unsigned int)b * CAP;
            const unsigned int e1 = gcur[b];
            for (unsigned int e = e0 + t; e < e1; e += 256)
                atomicAdd(&su.sort.cur[recs[e] >> 17], 1u);   // native u32 LDS
            __syncthreads();
            const unsigned int c0 = su.sort.cur[2 * t];
            const unsigned int c1 = su.sort.cur[2 * t + 1];
            const unsigned int loc = c0 + c1;
            unsigned int xs = loc;
#pragma unroll
            for (int o = 1; o < 64; o <<= 1) {
                unsigned int y = __shfl_up(xs, o, 64);
                if (lane >= o) xs += y;
            }
            if (lane == 63) su.sort.wsum[wid] = xs;
            __syncthreads();
            if (t == 0) {
                unsigned int run = 0;
#pragma unroll
                for (int i = 0; i < 4; ++i) { unsigned int tmp = su.sort.wsum[i]; su.sort.wsum[i] = run; run += tmp; }
            }
            __syncthreads();
            const unsigned int start0 = e0 + su.sort.wsum[wid] + xs - loc;
            const unsigned int start1 = start0 + c0;
            const int v0 = b * BNODES + 2 * t;
            if (v0 < N)     { dis[v0] = rsqrtf(1.0f + (float)c0); rp[v0] = (c0 << 24) | start0; }
            if (v0 + 1 < N) { dis[v0 + 1] = rsqrtf(1.0f + (float)c1); rp[v0 + 1] = (c1 << 24) | start1; }
            __syncthreads();
            su.sort.cur[2 * t] = start0;
            su.sort.cur[2 * t + 1] = start1;
            __syncthreads();
            for (unsigned int e = e0 + t; e < e1; e += 256) {
                unsigned int r = recs[e];                              // L2-hot
                unsigned int slot = atomicAdd(&su.sort.cur[r >> 17], 1u);
                recs2[slot] = r & 0x1FFFFu;                            // src only
            }
            __syncthreads();
        }
    }
    grid.sync();

    // ---- phase 3: hs1 = (x @ W1) * dis  (fp16 table) --------------------
    {
        const int n = t >> 4, j = t & 15;
        su.mv.ws[n][j] = W1[t];
        __syncthreads();
        const int ntiles = (N + 15) / 16;
        for (int tile = blk; tile < ntiles; tile += nblk) {
            const int node = tile * 16 + n;
            su.mv.xs[n][j] = (node < N) ? x[node * F + j] : 0.0f;
            __syncthreads();
            float acc = 0.f;
#pragma unroll
            for (int k = 0; k < 16; ++k) acc += su.mv.xs[n][k] * su.mv.ws[k][j];
            if (node < N) hs1[node * F + j] = __float2half(acc * dis[node]);
            __syncthreads();
        }
    }
    grid.sync();

    // ---- phase 4: layer-1 aggregation + relu + W2 matvec ----------------
    {
        const int j = t & 15, g = t >> 4;
        su.agg.ws[g][j] = W2[t];
        __syncthreads();
        const __half2* h1 = (const __half2*)hs1;
        const int j2 = t & 7, g8 = t >> 3;
        const int nchunks = (N + NPB - 1) / NPB;
        for (int chunk = blk; chunk < nchunks; chunk += nblk) {
            const int v0 = chunk * NPB;
#pragma unroll
            for (int it = 0; it < 4; ++it) {
                const int n = g8 + 32 * it;
                const int v = v0 + n;
                float sx = 0.f, sy = 0.f, dv = 0.f;
                if (v < N) {
                    dv = dis[v];
                    const unsigned int w = rp[v];
                    unsigned int e = w & 0xFFFFFFu;
                    const unsigned int e1 = e + (w >> 24);
                    float2 s = h2f2(h1[(size_t)v * 8 + j2]);   // self-loop
                    sx = s.x; sy = s.y;
                    for (; e + 8 <= e1; e += 8) {              // 8 independent rows
                        unsigned int r0 = recs2[e + 0], r1 = recs2[e + 1];
                        unsigned int r2 = recs2[e + 2], r3 = recs2[e + 3];
                        unsigned int r4 = recs2[e + 4], r5 = recs2[e + 5];
                        unsigned int r6 = recs2[e + 6], r7 = recs2[e + 7];
                        float2 a0 = h2f2(h1[r0 * 8 + j2]), a1 = h2f2(h1[r1 * 8 + j2]);
                        float2 a2 = h2f2(h1[r2 * 8 + j2]), a3 = h2f2(h1[r3 * 8 + j2]);
                        float2 a4 = h2f2(h1[r4 * 8 + j2]), a5 = h2f2(h1[r5 * 8 + j2]);
                        float2 a6 = h2f2(h1[r6 * 8 + j2]), a7 = h2f2(h1[r7 * 8 + j2]);
                        sx += ((a0.x + a1.x) + (a2.x + a3.x)) + ((a4.x + a5.x) + (a6.x + a7.x));
                        sy += ((a0.y + a1.y) + (a2.y + a3.y)) + ((a4.y + a5.y) + (a6.y + a7.y));
                    }
                    for (; e < e1; ++e) {
                        float2 a = h2f2(h1[recs2[e] * 8 + j2]);
                        sx += a.x; sy += a.y;
                    }
                }
                su.agg.hbf[n][2 * j2 + 0] = fmaxf(dv * sx + b1[2 * j2 + 0], 0.f);
                su.agg.hbf[n][2 * j2 + 1] = fmaxf(dv * sy + b1[2 * j2 + 1], 0.f);
            }
            __syncthreads();
#pragma unroll
            for (int it = 0; it < 8; ++it) {
                const int n = g + 16 * it;
                const int v = v0 + n;
                if (v < N) {
                    float acc = 0.f;
#pragma unroll
                    for (int k = 0; k < 16; ++k) acc += su.agg.hbf[n][k] * su.agg.ws[k][j];
                    hs2[(size_t)v * F + j] = __float2half(acc * dis[v]);
                }
            }
            __syncthreads();
        }
    }
    grid.sync();

    // ---- phase 5: layer-2 aggregation + relu + FC head ------------------
    {
        const __half2* h2 = (const __half2*)hs2;
        const int j2 = t & 7, g8 = t >> 3;
        const float wfx = Wfc[2 * j2 + 0], wfy = Wfc[2 * j2 + 1];
        const float bbx = b2[2 * j2 + 0], bby = b2[2 * j2 + 1];
        const float bf = bfc[0];
        const int nchunks = (N + NPB - 1) / NPB;
        for (int chunk = blk; chunk < nchunks; chunk += nblk) {
            const int v0 = chunk * NPB;
#pragma unroll
            for (int it = 0; it < 4; ++it) {
                const int v = v0 + g8 + 32 * it;
                if (v >= N) continue;
                const unsigned int w = rp[v];
                unsigned int e = w & 0xFFFFFFu;
                const unsigned int e1 = e + (w >> 24);
                float2 s0 = h2f2(h2[(size_t)v * 8 + j2]);
                float sx = s0.x, sy = s0.y;
                for (; e + 8 <= e1; e += 8) {
                    unsigned int r0 = recs2[e + 0], r1 = recs2[e + 1];
                    unsigned int r2 = recs2[e + 2], r3 = recs2[e + 3];
                    unsigned int r4 = recs2[e + 4], r5 = recs2[e + 5];
                    unsigned int r6 = recs2[e + 6], r7 = recs2[e + 7];
                    float2 a0 = h2f2(h2[r0 * 8 + j2]), a1 = h2f2(h2[r1 * 8 + j2]);
                    float2 a2 = h2f2(h2[r2 * 8 + j2]), a3 = h2f2(h2[r3 * 8 + j2]);
                    float2 a4 = h2f2(h2[r4 * 8 + j2]), a5 = h2f2(h2[r5 * 8 + j2]);
                    float2 a6 = h2f2(h2[r6 * 8 + j2]), a7 = h2f2(h2[r7 * 8 + j2]);
                    sx += ((a0.x + a1.x) + (a2.x + a3.x)) + ((a4.x + a5.x) + (a6.x + a7.x));
                    sy += ((a0.y + a1.y) + (a2.y + a3.y)) + ((a4.y + a5.y) + (a6.y + a7.y));
                }
                for (; e < e1; ++e) {
                    float2 a = h2f2(h2[recs2[e] * 8 + j2]);
                    sx += a.x; sy += a.y;
                }
                const float dv = dis[v];
                float h = fmaxf(dv * sx + bbx, 0.f) * wfx + fmaxf(dv * sy + bby, 0.f) * wfy;
                h += __shfl_down(h, 4, 8);
                h += __shfl_down(h, 2, 8);
                h += __shfl_down(h, 1, 8);
                if (j2 == 0) out[v] = h + bf;
            }
        }
    }
}

// ======================= fallback 6-kernel chain (R9) ====================
__global__ void ginit_kernel(unsigned int* __restrict__ gcur, int K) {
    int i = threadIdx.x;
    if (i < K) gcur[i] = (unsigned int)i * CAP;
}

__global__ void __launch_bounds__(256)
partition_kernel(const int* __restrict__ src, const int* __restrict__ dst,
                 unsigned int* __restrict__ gcur, unsigned int* __restrict__ recs,
                 int E, int K) {
    __shared__ unsigned int hist[K_MAX];
    __shared__ unsigned int offs[K_MAX];
    __shared__ unsigned int gbase[K_MAX];
    __shared__ unsigned int drec[PT];
    __shared__ unsigned char dbuk[PT];
    const int t = threadIdx.x;
    const int tile0 = blockIdx.x * PT;
    const int cnt = min(PT, E - tile0);
    if (t < K) hist[t] = 0u;
    __syncthreads();
    unsigned int rec[8], bp[8];
#pragma unroll
    for (int k = 0; k < 8; ++k) {
        int i = t + k * 256;
        bp[k] = 0xFFFFFFFFu;
        if (i < cnt) {
            int e = tile0 + i;
            unsigned int d = (unsigned int)dst[e];
            unsigned int s = (unsigned int)src[e];
            unsigned int b = d >> 9;
            rec[k] = ((d & 511u) << 17) | s;
            unsigned int pos = atomicAdd(&hist[b], 1u);
            bp[k] = (b << 12) | pos;
        }
    }
    __syncthreads();
    if (t < K) gbase[t] = atomicAdd(&gcur[t], hist[t]);
    if (t == 0) {
        unsigned int run = 0;
        for (int i = 0; i < K; ++i) { offs[i] = run; run += hist[i]; }
    }
    __syncthreads();
#pragma unroll
    for (int k = 0; k < 8; ++k) {
        if (bp[k] != 0xFFFFFFFFu) {
            unsigned int b = bp[k] >> 12, pos = bp[k] & 0xFFFu;
            unsigned int idx = offs[b] + pos;
            drec[idx] = rec[k];
            dbuk[idx] = (unsigned char)b;
        }
    }
    __syncthreads();
    for (int i = t; i < cnt; i += 256) {
        unsigned int b = dbuk[i];
        recs[gbase[b] + ((unsigned int)i - offs[b])] = drec[i];
    }
}

__global__ void __launch_bounds__(512)
sort_kernel(const unsigned int* __restrict__ recs, const unsigned int* __restrict__ gcur,
            float* __restrict__ dis, unsigned int* __restrict__ rp,
            unsigned int* __restrict__ recs2, int N) {
    __shared__ unsigned int cur[BNODES];
    __shared__ unsigned int wsum[8];
    const int b = blockIdx.x;
    const int t = threadIdx.x;
    const int lane = t & 63, wid = t >> 6;
    cur[t] = 0u;
    __syncthreads();
    const unsigned int e0 = (unsigned int)b * CAP;
    const unsigned int e1 = gcur[b];
    for (unsigned int e = e0 + t; e < e1; e += 512)
        atomicAdd(&cur[recs[e] >> 17], 1u);
    __syncthreads();
    const unsigned int c = cur[t];
    unsigned int x = c;
#pragma unroll
    for (int o = 1; o < 64; o <<= 1) {
        unsigned int y = __shfl_up(x, o, 64);
        if (lane >= o) x += y;
    }
    if (lane == 63) wsum[wid] = x;
    __syncthreads();
    if (t == 0) {
        unsigned int run = 0;
#pragma unroll
        for (int i = 0; i < 8; ++i) { unsigned int tmp = wsum[i]; wsum[i] = run; run += tmp; }
    }
    __syncthreads();
    const unsigned int start = e0 + wsum[wid] + x - c;
    const int v = b * BNODES + t;
    if (v < N) {
        dis[v] = rsqrtf(1.0f + (float)c);
        rp[v] = (c << 24) | start;
    }
    __syncthreads();
    cur[t] = start;
    __syncthreads();
    for (unsigned int e = e0 + t; e < e1; e += 512) {
        unsigned int r = recs[e];
        unsigned int slot = atomicAdd(&cur[r >> 17], 1u);
        recs2[slot] = r & 0x1FFFFu;
    }
}

__global__ void mv_scale_kernel(const float* __restrict__ x, const float* __restrict__ W,
                                const float* __restrict__ dis, __half* __restrict__ hs, int N) {
    __shared__ float xs[16][17];
    __shared__ float ws[16][16];
    int tid = threadIdx.x;
    int n = tid >> 4, j = tid & 15;
    int node = blockIdx.x * 16 + n;
    ws[n][j] = W[tid];
    xs[n][j] = (node < N) ? x[node * F + j] : 0.0f;
    __syncthreads();
    float acc = 0.f;
#pragma unroll
    for (int k = 0; k < 16; ++k) acc += xs[n][k] * ws[k][j];
    if (node < N) hs[node * F + j] = __float2half(acc * dis[node]);
}

__global__ void __launch_bounds__(256)
agg1_kernel(const unsigned int* __restrict__ recs2, const unsigned int* __restrict__ rp,
            const __half2* __restrict__ hs1, const float* __restrict__ dis,
            const float* __restrict__ W2, const float* __restrict__ b1,
            __half* __restrict__ hs2, int N) {
    __shared__ float ws[16][16];
    __shared__ float hbf[NPB][17];
    const int t = threadIdx.x;
    ws[t >> 4][t & 15] = W2[t];
    const int j2 = t & 7;
    const int g8 = t >> 3;
    const int v0 = blockIdx.x * NPB;
#pragma unroll
    for (int it = 0; it < 4; ++it) {
        const int n = g8 + 32 * it;
        const int v = v0 + n;
        float sx = 0.f, sy = 0.f, dv = 0.f;
        if (v < N) {
            dv = dis[v];
            const unsigned int w = rp[v];
            unsigned int e = w & 0xFFFFFFu;
            const unsigned int e1 = e + (w >> 24);
            float2 s = h2f2(hs1[(size_t)v * 8 + j2]);
            sx = s.x; sy = s.y;
            for (; e + 8 <= e1; e += 8) {
                unsigned int r0 = recs2[e + 0], r1 = recs2[e + 1];
                unsigned int r2 = recs2[e + 2], r3 = recs2[e + 3];
                unsigned int r4 = recs2[e + 4], r5 = recs2[e + 5];
                unsigned int r6 = recs2[e + 6], r7 = recs2[e + 7];
                float2 a0 = h2f2(hs1[r0 * 8 + j2]), a1 = h2f2(hs1[r1 * 8 + j2]);
                float2 a2 = h2f2(hs1[r2 * 8 + j2]), a3 = h2f2(hs1[r3 * 8 + j2]);
                float2 a4 = h2f2(hs1[r4 * 8 + j2]), a5 = h2f2(hs1[r5 * 8 + j2]);
                float2 a6 = h2f2(hs1[r6 * 8 + j2]), a7 = h2f2(hs1[r7 * 8 + j2]);
                sx += ((a0.x + a1.x) + (a2.x + a3.x)) + ((a4.x + a5.x) + (a6.x + a7.x));
                sy += ((a0.y + a1.y) + (a2.y + a3.y)) + ((a4.y + a5.y) + (a6.y + a7.y));
            }
            for (; e < e1; ++e) {
                float2 a = h2f2(hs1[recs2[e] * 8 + j2]);
                sx += a.x; sy += a.y;
            }
        }
        hbf[n][2 * j2 + 0] = fmaxf(dv * sx + b1[2 * j2 + 0], 0.f);
        hbf[n][2 * j2 + 1] = fmaxf(dv * sy + b1[2 * j2 + 1], 0.f);
    }
    __syncthreads();
    const int j = t & 15;
    const int g = t >> 4;
#pragma unroll
    for (int it = 0; it < 8; ++it) {
        const int n = g + 16 * it;
        const int v = v0 + n;
        if (v >= N) continue;
        float acc = 0.f;
#pragma unroll
        for (int k = 0; k < 16; ++k) acc += hbf[n][k] * ws[k][j];
        hs2[(size_t)v * F + j] = __float2half(acc * dis[v]);
    }
}

__global__ void __launch_bounds__(256)
agg2_kernel(const unsigned int* __restrict__ recs2, const unsigned int* __restrict__ rp,
            const __half2* __restrict__ hs2, const float* __restrict__ dis,
            const float* __restrict__ b2, const float* __restrict__ Wfc,
            const float* __restrict__ bfc, float* __restrict__ out, int N) {
    const int t = threadIdx.x;
    const int j2 = t & 7;
    const int g8 = t >> 3;
    const int v0 = blockIdx.x * NPB;
    const float wfx = Wfc[2 * j2 + 0], wfy = Wfc[2 * j2 + 1];
    const float bbx = b2[2 * j2 + 0], bby = b2[2 * j2 + 1];
    const float bf = bfc[0];
#pragma unroll
    for (int it = 0; it < 4; ++it) {
        const int v = v0 + g8 + 32 * it;
        if (v >= N) continue;
        const unsigned int w = rp[v];
        unsigned int e = w & 0xFFFFFFu;
        const unsigned int e1 = e + (w >> 24);
        float2 s0 = h2f2(hs2[(size_t)v * 8 + j2]);
        float sx = s0.x, sy = s0.y;
        for (; e + 8 <= e1; e += 8) {
            unsigned int r0 = recs2[e + 0], r1 = recs2[e + 1];
            unsigned int r2 = recs2[e + 2], r3 = recs2[e + 3];
            unsigned int r4 = recs2[e + 4], r5 = recs2[e + 5];
            unsigned int r6 = recs2[e + 6], r7 = recs2[e + 7];
            float2 a0 = h2f2(hs2[r0 * 8 + j2]), a1 = h2f2(hs2[r1 * 8 + j2]);
            float2 a2 = h2f2(hs2[r2 * 8 + j2]), a3 = h2f2(hs2[r3 * 8 + j2]);
            float2 a4 = h2f2(hs2[r4 * 8 + j2]), a5 = h2f2(hs2[r5 * 8 + j2]);
            float2 a6 = h2f2(hs2[r6 * 8 + j2]), a7 = h2f2(hs2[r7 * 8 + j2]);
            sx += ((a0.x + a1.x) + (a2.x + a3.x)) + ((a4.x + a5.x) + (a6.x + a7.x));
            sy += ((a0.y + a1.y) + (a2.y + a3.y)) + ((a4.y + a5.y) + (a6.y + a7.y));
        }
        for (; e < e1; ++e) {
            float2 a = h2f2(hs2[recs2[e] * 8 + j2]);
            sx += a.x; sy += a.y;
        }
        const float dv = dis[v];
        float h = fmaxf(dv * sx + bbx, 0.f) * wfx + fmaxf(dv * sy + bby, 0.f) * wfy;
        h += __shfl_down(h, 4, 8);
        h += __shfl_down(h, 2, 8);
        h += __shfl_down(h, 1, 8);
        if (j2 == 0) out[v] = h + bf;
    }
}

static inline char* align256(char* p) {
    return (char*)(((uintptr_t)p + 255) & ~(uintptr_t)255);
}

extern "C" void kernel_launch(void* const* d_in, const int* in_sizes, int n_in,
                              void* d_out, int out_size, void* d_ws, size_t ws_size,
                              hipStream_t stream) {
    const float* x   = (const float*)d_in[0];
    const int*   ei  = (const int*)d_in[1];
    const float* W1  = (const float*)d_in[2];
    const float* b1  = (const float*)d_in[3];
    const float* W2  = (const float*)d_in[4];
    const float* b2  = (const float*)d_in[5];
    const float* Wfc = (const float*)d_in[6];
    const float* bfc = (const float*)d_in[7];
    float* out = (float*)d_out;

    int N = in_sizes[0] / F;        // 100000
    int E = in_sizes[1] / 2;        // 3200000
    const int* src = ei;
    const int* dst = ei + E;
    int K = (N + BNODES - 1) / BNODES;   // 196

    // 256-B-aligned layout (R2 lesson). recs (pass scratch) is consumed
    // before hs1|hs2 overwrite it (6.4MB < 14.4MB).
    char* p = (char*)d_ws;
    float* dis = (float*)align256(p);                   p = (char*)(dis + N);
    unsigned int* gcur  = (unsigned int*)align256(p);   p = (char*)(gcur + K);
    unsigned int* rp    = (unsigned int*)align256(p);   p = (char*)(rp + N);
    unsigned int* recs2 = (unsigned int*)align256(p);   p = (char*)(recs2 + (size_t)K * CAP);
    unsigned int* recs  = (unsigned int*)align256(p);
    __half* hs1 = (__half*)recs;                        // reuse after sort
    __half* hs2 = hs1 + (size_t)N * F;

    // ---- try the fused cooperative kernel with runtime-sized grid -------
    int nb = 0;
    hipError_t qerr = hipOccupancyMaxActiveBlocksPerMultiprocessor(
        &nb, (const void*)fused_kernel, 256, 0);
    hipError_t lerr = hipErrorUnknown;
    if (qerr == hipSuccess && nb > 0) {
        int grid = nb * 256;                    // nb blocks/CU x 256 CUs
        void* args[] = { &src, &dst, &x, &W1, &b1, &W2, &b2, &Wfc, &bfc, &out,
                         &gcur, &rp, &recs, &recs2, &dis, &hs1, &hs2, &N, &E, &K };
        lerr = hipLaunchCooperativeKernel((void*)fused_kernel, dim3(grid),
                                          dim3(256), args, 0, stream);
    }
    if (lerr != hipSuccess) {
        // ---- fallback: proven 6-kernel chain (R9) -----------------------
        const int T = 256;
        ginit_kernel<<<1, T, 0, stream>>>(gcur, K);
        partition_kernel<<<(E + PT - 1) / PT, T, 0, stream>>>(src, dst, gcur, recs, E, K);
        sort_kernel<<<K, 512, 0, stream>>>(recs, gcur, dis, rp, recs2, N);
        mv_scale_kernel<<<(N + 15) / 16, T, 0, stream>>>(x, W1, dis, hs1, N);
        agg1_kernel<<<(N + NPB - 1) / NPB, T, 0, stream>>>(recs2, rp, (const __half2*)hs1, dis, W2, b1, hs2, N);
        agg2_kernel<<<(N + NPB - 1) / NPB, T, 0, stream>>>(recs2, rp, (const __half2*)hs2, dis, b2, Wfc, bfc, out, N);
    }
}

// Round 12
// 197.077 us; speedup vs baseline: 3.3002x; 3.3002x over previous
//
#include <hip/hip_runtime.h>
#include <hip/hip_fp16.h>
#include <stdint.h>

// GCN: out = relu(Ahat @ (X W1) + b1) -> relu(Ahat @ (. W2) + b2) -> @ Wfc + bfc
// Ahat = D^-1/2 (A+I) D^-1/2.
// Identity: layer(v) = dis[v] * ( sum_{e: dst=v} hs[src_e] + hs[v] ),
// hs[i] = (x[i] @ W) * dis[i].  Self-loops analytic.
//
// Cost model (R1..R11 measured):
//  - atomic-free CSR aggregation (R6), fp16 hs tables < 4MB XCD L2 (R8);
//  - R11: cooperative grid.sync() at ~2048 blocks costs ~150us/sync on
//    gfx950 (5x slower than the kernel chain) -> launch gaps (~10-15us) are
//    the cheaper glue. Minimize launches, don't fuse with grid barriers.
// R12: 6 kernels -> 4 + tiny memset (relative cursors kill ginit; sort+mv
// fused block-locally, hs un-aliased from recs); agg NPB 128->32 (grid 3125,
// ~12 blocks/CU) to fix the 52%-occupancy latency stall in the gathers.

constexpr int F = 16;
constexpr int K_MAX = 256;           // max buckets
constexpr int BNODES = 512;          // nodes per bucket  (bucket = dst >> 9)
constexpr int PT = 4096;             // edges per partition tile (16/thread)
constexpr int NPB = 32;              // nodes per block in aggregation
constexpr unsigned int CAP = 18432;  // bucket capacity (mean 16327, +16 sigma)

__device__ __forceinline__ float2 h2f2(__half2 h) { return __half22float2(h); }

// ---- pass 1: deterministic tile partition, grouped by bucket ------------
// rec = (dst_local << 17) | src   (N < 2^17, dst_local < 512)
// gcur holds RELATIVE cursors (memset 0); absolute base = b*CAP + cursor.
__global__ void __launch_bounds__(256)
partition_kernel(const int* __restrict__ src, const int* __restrict__ dst,
                 unsigned int* __restrict__ gcur, unsigned int* __restrict__ recs,
                 int E, int K) {
    __shared__ unsigned int hist[K_MAX];
    __shared__ unsigned int offs[K_MAX];
    __shared__ unsigned int gbase[K_MAX];
    __shared__ unsigned int drec[PT];
    __shared__ unsigned char dbuk[PT];
    const int t = threadIdx.x;
    const int tile0 = blockIdx.x * PT;
    const int cnt = min(PT, E - tile0);
    if (t < K) hist[t] = 0u;
    __syncthreads();
    unsigned int rec[16], bp[16];
#pragma unroll
    for (int k = 0; k < 16; ++k) {
        int i = t + k * 256;                      // coalesced
        bp[k] = 0xFFFFFFFFu;
        if (i < cnt) {
            int e = tile0 + i;
            unsigned int d = (unsigned int)dst[e];
            unsigned int s = (unsigned int)src[e];
            unsigned int b = d >> 9;
            rec[k] = ((d & 511u) << 17) | s;
            unsigned int pos = atomicAdd(&hist[b], 1u);   // pos < PT (12 bits)
            bp[k] = (b << 12) | pos;
        }
    }
    __syncthreads();
    if (t < K) gbase[t] = (unsigned int)t * CAP + atomicAdd(&gcur[t], hist[t]);
    if (t == 0) {
        unsigned int run = 0;
        for (int i = 0; i < K; ++i) { offs[i] = run; run += hist[i]; }
    }
    __syncthreads();
#pragma unroll
    for (int k = 0; k < 16; ++k) {
        if (bp[k] != 0xFFFFFFFFu) {
            unsigned int b = bp[k] >> 12, pos = bp[k] & 0xFFFu;
            unsigned int idx = offs[b] + pos;
            drec[idx] = rec[k];
            dbuk[idx] = (unsigned char)b;
        }
    }
    __syncthreads();
    for (int i = t; i < cnt; i += 256) {          // coalesced within runs
        unsigned int b = dbuk[i];
        recs[gbase[b] + ((unsigned int)i - offs[b])] = drec[i];
    }
}

// ---- pass 2: counting sort -> CSR + dis + packed rows, THEN hs1 ---------
// Block b owns nodes [b*512, b*512+512): degrees from its own recs (L2-hot),
// block-scan -> starts; dis + rp = (deg<<24)|start; scatter recs -> recs2;
// finally hs1 = (x @ W1) * dis for the same nodes (block-local, fused to
// kill one launch gap).  hs1 does NOT alias recs (other blocks still read).
__global__ void __launch_bounds__(512)
sort_mv_kernel(const unsigned int* __restrict__ recs, const unsigned int* __restrict__ gcur,
               const float* __restrict__ x, const float* __restrict__ W1,
               float* __restrict__ dis, unsigned int* __restrict__ rp,
               unsigned int* __restrict__ recs2, __half* __restrict__ hs1, int N) {
    __shared__ unsigned int cur[BNODES];
    __shared__ unsigned int wsum[8];
    __shared__ float sdis[BNODES];
    __shared__ float ws[16][16];
    __shared__ float xs[32][17];
    const int b = blockIdx.x;
    const int t = threadIdx.x;
    const int lane = t & 63, wid = t >> 6;
    cur[t] = 0u;
    if (t < 256) ws[t >> 4][t & 15] = W1[t];
    __syncthreads();
    const unsigned int e0 = (unsigned int)b * CAP;
    const unsigned int e1 = e0 + gcur[b];         // bucket end (relative cursor)
    for (unsigned int e = e0 + t; e < e1; e += 512)
        atomicAdd(&cur[recs[e] >> 17], 1u);       // native u32 LDS
    __syncthreads();
    const unsigned int c = cur[t];
    unsigned int xsc = c;
#pragma unroll
    for (int o = 1; o < 64; o <<= 1) {
        unsigned int y = __shfl_up(xsc, o, 64);
        if (lane >= o) xsc += y;
    }
    if (lane == 63) wsum[wid] = xsc;
    __syncthreads();
    if (t == 0) {
        unsigned int run = 0;
#pragma unroll
        for (int i = 0; i < 8; ++i) { unsigned int tmp = wsum[i]; wsum[i] = run; run += tmp; }
    }
    __syncthreads();
    const unsigned int start = e0 + wsum[wid] + xsc - c;   // exclusive prefix
    const int v = b * BNODES + t;
    const float dv = rsqrtf(1.0f + (float)c);
    sdis[t] = dv;
    if (v < N) {
        dis[v] = dv;
        rp[v] = (c << 24) | start;                // start < K*CAP=3.61M < 2^24
    }
    __syncthreads();
    cur[t] = start;                               // reuse as write cursors
    __syncthreads();
    for (unsigned int e = e0 + t; e < e1; e += 512) {
        unsigned int r = recs[e];                          // coalesced, L2-hot
        unsigned int slot = atomicAdd(&cur[r >> 17], 1u);  // native u32 LDS
        recs2[slot] = r & 0x1FFFFu;                        // src only
    }
    // ---- fused mv: hs1 for this block's 512 nodes -----------------------
    const int n = t >> 4, j = t & 15;             // 32 nodes per pass
#pragma unroll
    for (int tile = 0; tile < 16; ++tile) {
        const int loc = tile * 32 + n;
        const int node = b * BNODES + loc;
        __syncthreads();
        xs[n][j] = (node < N) ? x[(size_t)node * F + j] : 0.0f;
        __syncthreads();
        float acc = 0.f;
#pragma unroll
        for (int k = 0; k < 16; ++k) acc += xs[n][k] * ws[k][j];
        if (node < N) hs1[(size_t)node * F + j] = __float2half(acc * sdis[loc]);
    }
}

// ---- layer-1 aggregation + relu + W2 matvec (zero atomics) --------------
// 8-lane __half2 groups; NPB=32 nodes/block -> grid ~3125 (~12 blocks/CU).
__global__ void __launch_bounds__(256)
agg1_kernel(const unsigned int* __restrict__ recs2, const unsigned int* __restrict__ rp,
            const __half2* __restrict__ hs1, const float* __restrict__ dis,
            const float* __restrict__ W2, const float* __restrict__ b1,
            __half* __restrict__ hs2, int N) {
    __shared__ float ws[16][16];
    __shared__ float hbf[NPB][17];
    const int t = threadIdx.x;
    ws[t >> 4][t & 15] = W2[t];
    const int j2 = t & 7;
    const int g8 = t >> 3;
    const int v0 = blockIdx.x * NPB;
    {
        const int v = v0 + g8;
        float sx = 0.f, sy = 0.f, dv = 0.f;
        if (v < N) {
            dv = dis[v];
            const unsigned int w = rp[v];
            unsigned int e = w & 0xFFFFFFu;
            const unsigned int e1 = e + (w >> 24);
            float2 s = h2f2(hs1[(size_t)v * 8 + j2]);       // self-loop term
            sx = s.x; sy = s.y;
            for (; e + 8 <= e1; e += 8) {                   // 8 independent rows
                unsigned int r0 = recs2[e + 0], r1 = recs2[e + 1];
                unsigned int r2 = recs2[e + 2], r3 = recs2[e + 3];
                unsigned int r4 = recs2[e + 4], r5 = recs2[e + 5];
                unsigned int r6 = recs2[e + 6], r7 = recs2[e + 7];
                float2 a0 = h2f2(hs1[r0 * 8 + j2]), a1 = h2f2(hs1[r1 * 8 + j2]);
                float2 a2 = h2f2(hs1[r2 * 8 + j2]), a3 = h2f2(hs1[r3 * 8 + j2]);
                float2 a4 = h2f2(hs1[r4 * 8 + j2]), a5 = h2f2(hs1[r5 * 8 + j2]);
                float2 a6 = h2f2(hs1[r6 * 8 + j2]), a7 = h2f2(hs1[r7 * 8 + j2]);
                sx += ((a0.x + a1.x) + (a2.x + a3.x)) + ((a4.x + a5.x) + (a6.x + a7.x));
                sy += ((a0.y + a1.y) + (a2.y + a3.y)) + ((a4.y + a5.y) + (a6.y + a7.y));
            }
            for (; e < e1; ++e) {
                float2 a = h2f2(hs1[recs2[e] * 8 + j2]);
                sx += a.x; sy += a.y;
            }
        }
        hbf[g8][2 * j2 + 0] = fmaxf(dv * sx + b1[2 * j2 + 0], 0.f);
        hbf[g8][2 * j2 + 1] = fmaxf(dv * sy + b1[2 * j2 + 1], 0.f);
    }
    __syncthreads();
    const int j = t & 15;
    const int g = t >> 4;
#pragma unroll
    for (int it = 0; it < 2; ++it) {
        const int n = g + 16 * it;
        const int v = v0 + n;
        if (v >= N) continue;
        float acc = 0.f;
#pragma unroll
        for (int k = 0; k < 16; ++k) acc += hbf[n][k] * ws[k][j];
        hs2[(size_t)v * F + j] = __float2half(acc * dis[v]);
    }
}

// ---- layer-2 aggregation + relu + FC head -------------------------------
__global__ void __launch_bounds__(256)
agg2_kernel(const unsigned int* __restrict__ recs2, const unsigned int* __restrict__ rp,
            const __half2* __restrict__ hs2, const float* __restrict__ dis,
            const float* __restrict__ b2, const float* __restrict__ Wfc,
            const float* __restrict__ bfc, float* __restrict__ out, int N) {
    const int t = threadIdx.x;
    const int j2 = t & 7;
    const int g8 = t >> 3;
    const int v0 = blockIdx.x * NPB;
    const float wfx = Wfc[2 * j2 + 0], wfy = Wfc[2 * j2 + 1];
    const float bbx = b2[2 * j2 + 0], bby = b2[2 * j2 + 1];
    const float bf = bfc[0];
    const int v = v0 + g8;
    if (v >= N) return;
    const unsigned int w = rp[v];
    unsigned int e = w & 0xFFFFFFu;
    const unsigned int e1 = e + (w >> 24);
    float2 s0 = h2f2(hs2[(size_t)v * 8 + j2]);
    float sx = s0.x, sy = s0.y;
    for (; e + 8 <= e1; e += 8) {
        unsigned int r0 = recs2[e + 0], r1 = recs2[e + 1];
        unsigned int r2 = recs2[e + 2], r3 = recs2[e + 3];
        unsigned int r4 = recs2[e + 4], r5 = recs2[e + 5];
        unsigned int r6 = recs2[e + 6], r7 = recs2[e + 7];
        float2 a0 = h2f2(hs2[r0 * 8 + j2]), a1 = h2f2(hs2[r1 * 8 + j2]);
        float2 a2 = h2f2(hs2[r2 * 8 + j2]), a3 = h2f2(hs2[r3 * 8 + j2]);
        float2 a4 = h2f2(hs2[r4 * 8 + j2]), a5 = h2f2(hs2[r5 * 8 + j2]);
        float2 a6 = h2f2(hs2[r6 * 8 + j2]), a7 = h2f2(hs2[r7 * 8 + j2]);
        sx += ((a0.x + a1.x) + (a2.x + a3.x)) + ((a4.x + a5.x) + (a6.x + a7.x));
        sy += ((a0.y + a1.y) + (a2.y + a3.y)) + ((a4.y + a5.y) + (a6.y + a7.y));
    }
    for (; e < e1; ++e) {
        float2 a = h2f2(hs2[recs2[e] * 8 + j2]);
        sx += a.x; sy += a.y;
    }
    const float dv = dis[v];
    float h = fmaxf(dv * sx + bbx, 0.f) * wfx + fmaxf(dv * sy + bby, 0.f) * wfy;
    h += __shfl_down(h, 4, 8);
    h += __shfl_down(h, 2, 8);
    h += __shfl_down(h, 1, 8);
    if (j2 == 0) out[v] = h + bf;
}

static inline char* align256(char* p) {
    return (char*)(((uintptr_t)p + 255) & ~(uintptr_t)255);
}

extern "C" void kernel_launch(void* const* d_in, const int* in_sizes, int n_in,
                              void* d_out, int out_size, void* d_ws, size_t ws_size,
                              hipStream_t stream) {
    const float* x   = (const float*)d_in[0];
    const int*   ei  = (const int*)d_in[1];
    const float* W1  = (const float*)d_in[2];
    const float* b1  = (const float*)d_in[3];
    const float* W2  = (const float*)d_in[4];
    const float* b2  = (const float*)d_in[5];
    const float* Wfc = (const float*)d_in[6];
    const float* bfc = (const float*)d_in[7];
    float* out = (float*)d_out;

    const int N = in_sizes[0] / F;        // 100000
    const int E = in_sizes[1] / 2;        // 3200000
    const int* src = ei;
    const int* dst = ei + E;
    const int K = (N + BNODES - 1) / BNODES;   // 196

    // 256-B-aligned layout (R2 lesson). hs1/hs2 are NOT aliased with recs:
    // the fused sort_mv writes hs1 while other blocks still read their recs.
    char* p = (char*)d_ws;
    float* dis = (float*)align256(p);                   p = (char*)(dis + N);
    unsigned int* gcur  = (unsigned int*)align256(p);   p = (char*)(gcur + K);
    unsigned int* rp    = (unsigned int*)align256(p);   p = (char*)(rp + N);
    unsigned int* recs2 = (unsigned int*)align256(p);   p = (char*)(recs2 + (size_t)K * CAP);
    unsigned int* recs  = (unsigned int*)align256(p);   p = (char*)(recs + (size_t)K * CAP);
    __half* hs1 = (__half*)align256(p);                 p = (char*)(hs1 + (size_t)N * F);
    __half* hs2 = (__half*)align256(p);

    const int T = 256;

    hipMemsetAsync(gcur, 0, (size_t)K * sizeof(unsigned int), stream);
    partition_kernel<<<(E + PT - 1) / PT, T, 0, stream>>>(src, dst, gcur, recs, E, K);
    sort_mv_kernel<<<K, 512, 0, stream>>>(recs, gcur, x, W1, dis, rp, recs2, hs1, N);
    agg1_kernel<<<(N + NPB - 1) / NPB, T, 0, stream>>>(recs2, rp, (const __half2*)hs1, dis, W2, b1, hs2, N);
    agg2_kernel<<<(N + NPB - 1) / NPB, T, 0, stream>>>(recs2, rp, (const __half2*)hs2, dis, b2, Wfc, bfc, out, N);
}